// Round 14
// baseline (168.596 us; speedup 1.0000x reference)
//
#include <hip/hip_runtime.h>
#include <math.h>

#define N 512
#define NPAD(i) ((i) + ((i) >> 5))
#define FSZ 532
#define NCOL 257           // Hermitian: columns v = 0..256 only
#define NG2 33             // K2 column-groups per image (33*8 = 264 >= 257)
// mask: (u-256)^2 + (v-256)^2 <= 51.2^2 (integer dist^2 exact in fp32)
#define RAD2 2621.44f
#define SQ2H 0.70710678f

// ---------------------------------------------------------------------------
// Cross-lane primitives on the VALU pipe (gfx950). (R13 verbatim)
// ---------------------------------------------------------------------------
__device__ __forceinline__ void plswap32(float& x, float& y) {
    asm volatile("s_nop 1\n\tv_permlane32_swap_b32 %0, %1\n\ts_nop 1"
                 : "+v"(x), "+v"(y));
}
__device__ __forceinline__ void plswap16(float& x, float& y) {
    asm volatile("s_nop 1\n\tv_permlane16_swap_b32 %0, %1\n\ts_nop 1"
                 : "+v"(x), "+v"(y));
}
template <int PAT>
__device__ __forceinline__ float ds_swz(float v) {
    return __int_as_float(
        __builtin_amdgcn_ds_swizzle(__float_as_int(v), PAT));
}
template <int CTRL>
__device__ __forceinline__ float dppq(float v) {
    return __int_as_float(__builtin_amdgcn_update_dpp(
        0, __float_as_int(v), CTRL, 0xF, 0xF, false));
}

// ---------------------------------------------------------------------------
// In-register 8-point DFT, natural order in/out.
// ---------------------------------------------------------------------------
__device__ __forceinline__ void dft8(float (&xr)[8], float (&xi)[8]) {
    float e0r = xr[0] + xr[4], e0i = xi[0] + xi[4];
    float e1r = xr[0] - xr[4], e1i = xi[0] - xi[4];
    float e2r = xr[2] + xr[6], e2i = xi[2] + xi[6];
    float e3r = xr[2] - xr[6], e3i = xi[2] - xi[6];
    float E0r = e0r + e2r, E0i = e0i + e2i;
    float E2r = e0r - e2r, E2i = e0i - e2i;
    float E1r = e1r + e3i, E1i = e1i - e3r;
    float E3r = e1r - e3i, E3i = e1i + e3r;
    float o0r = xr[1] + xr[5], o0i = xi[1] + xi[5];
    float o1r = xr[1] - xr[5], o1i = xi[1] - xi[5];
    float o2r = xr[3] + xr[7], o2i = xi[3] + xi[7];
    float o3r = xr[3] - xr[7], o3i = xi[3] - xi[7];
    float O0r = o0r + o2r, O0i = o0i + o2i;
    float O2r = o0r - o2r, O2i = o0i - o2i;
    float O1r = o1r + o3i, O1i = o1i - o3r;
    float O3r = o1r - o3i, O3i = o1i + o3r;
    float t1r = SQ2H * (O1r + O1i), t1i = SQ2H * (O1i - O1r);
    float t2r = O2i,                t2i = -O2r;
    float t3r = SQ2H * (O3i - O3r), t3i = -SQ2H * (O3r + O3i);
    xr[0] = E0r + O0r; xi[0] = E0i + O0i;
    xr[4] = E0r - O0r; xi[4] = E0i - O0i;
    xr[1] = E1r + t1r; xi[1] = E1i + t1i;
    xr[5] = E1r - t1r; xi[5] = E1i - t1i;
    xr[2] = E2r + t2r; xi[2] = E2i + t2i;
    xr[6] = E2r - t2r; xi[6] = E2i - t2i;
    xr[3] = E3r + t3r; xi[3] = E3i + t3i;
    xr[7] = E3r - t3r; xi[7] = E3i - t3i;
}

// ---------------------------------------------------------------------------
// TWO interleaved wave-level 512-pt FFTs (R13 engine: permlane swaps for
// xor32/16, ds_swizzle for xor8/4, DPP quad_perm for xor2/1).
// Out: lane l, reg t holds X[br6(l) + 64*t].
// ---------------------------------------------------------------------------
__device__ __forceinline__ void fft512_x2(float (&ar)[8], float (&ai)[8],
                                          float (&br)[8], float (&bi)[8],
                                          int l) {
    {   // ---- stage 32 ----
        const int j = l & 31;
        const float f = (float)j * (1.0f / 64.0f);
        const float c = __builtin_amdgcn_cosf(f);
        const float s = __builtin_amdgcn_sinf(f);
        const bool up = (l & 32) != 0;
        const float sgn = up ? -1.0f : 1.0f;
        const float wc  = up ? c : 1.0f;
        const float ws  = up ? s : 0.0f;
#pragma unroll
        for (int k = 0; k < 8; ++k) {
            float xr = ar[k], yr = ar[k], xi = ai[k], yi = ai[k];
            float Xr = br[k], Yr = br[k], Xi = bi[k], Yi = bi[k];
            plswap32(xr, yr); plswap32(xi, yi);
            plswap32(Xr, Yr); plswap32(Xi, Yi);
            float tr = fmaf(sgn, yr, xr);
            float ti = fmaf(sgn, yi, xi);
            float ur = fmaf(sgn, Yr, Xr);
            float ui = fmaf(sgn, Yi, Xi);
            ar[k] = tr * wc + ti * ws;
            ai[k] = ti * wc - tr * ws;
            br[k] = ur * wc + ui * ws;
            bi[k] = ui * wc - ur * ws;
        }
    }
    {   // ---- stage 16 ----
        const int j = l & 15;
        const float f = (float)j * (1.0f / 32.0f);
        const float c = __builtin_amdgcn_cosf(f);
        const float s = __builtin_amdgcn_sinf(f);
        const bool up = (l & 16) != 0;
        const float sgn = up ? -1.0f : 1.0f;
        const float wc  = up ? c : 1.0f;
        const float ws  = up ? s : 0.0f;
#pragma unroll
        for (int k = 0; k < 8; ++k) {
            float xr = ar[k], yr = ar[k], xi = ai[k], yi = ai[k];
            float Xr = br[k], Yr = br[k], Xi = bi[k], Yi = bi[k];
            plswap16(xr, yr); plswap16(xi, yi);
            plswap16(Xr, Yr); plswap16(Xi, Yi);
            float tr = fmaf(sgn, yr, xr);
            float ti = fmaf(sgn, yi, xi);
            float ur = fmaf(sgn, Yr, Xr);
            float ui = fmaf(sgn, Yi, Xi);
            ar[k] = tr * wc + ti * ws;
            ai[k] = ti * wc - tr * ws;
            br[k] = ur * wc + ui * ws;
            bi[k] = ui * wc - ur * ws;
        }
    }
    {   // ---- stage 8: ds_swizzle xor8 ----
        const int j = l & 7;
        const float f = (float)j * (1.0f / 16.0f);
        const float c = __builtin_amdgcn_cosf(f);
        const float s = __builtin_amdgcn_sinf(f);
        const bool up = (l & 8) != 0;
        const float sgn = up ? -1.0f : 1.0f;
        const float wc  = up ? c : 1.0f;
        const float ws  = up ? s : 0.0f;
#pragma unroll
        for (int k = 0; k < 8; ++k) {
            float pr = ds_swz<0x201F>(ar[k]);
            float pi = ds_swz<0x201F>(ai[k]);
            float qr = ds_swz<0x201F>(br[k]);
            float qi = ds_swz<0x201F>(bi[k]);
            float tr = fmaf(sgn, ar[k], pr);
            float ti = fmaf(sgn, ai[k], pi);
            float ur = fmaf(sgn, br[k], qr);
            float ui = fmaf(sgn, bi[k], qi);
            ar[k] = tr * wc + ti * ws;
            ai[k] = ti * wc - tr * ws;
            br[k] = ur * wc + ui * ws;
            bi[k] = ui * wc - ur * ws;
        }
    }
    {   // ---- stage 4: ds_swizzle xor4 ----
        const int j = l & 3;
        const float f = (float)j * (1.0f / 8.0f);
        const float c = __builtin_amdgcn_cosf(f);
        const float s = __builtin_amdgcn_sinf(f);
        const bool up = (l & 4) != 0;
        const float sgn = up ? -1.0f : 1.0f;
        const float wc  = up ? c : 1.0f;
        const float ws  = up ? s : 0.0f;
#pragma unroll
        for (int k = 0; k < 8; ++k) {
            float pr = ds_swz<0x101F>(ar[k]);
            float pi = ds_swz<0x101F>(ai[k]);
            float qr = ds_swz<0x101F>(br[k]);
            float qi = ds_swz<0x101F>(bi[k]);
            float tr = fmaf(sgn, ar[k], pr);
            float ti = fmaf(sgn, ai[k], pi);
            float ur = fmaf(sgn, br[k], qr);
            float ui = fmaf(sgn, bi[k], qi);
            ar[k] = tr * wc + ti * ws;
            ai[k] = ti * wc - tr * ws;
            br[k] = ur * wc + ui * ws;
            bi[k] = ui * wc - ur * ws;
        }
    }
    {   // ---- stage 2: DPP quad_perm [2,3,0,1] ----
        const int j = l & 1;
        const float f = (float)j * 0.25f;
        const float c = __builtin_amdgcn_cosf(f);
        const float s = __builtin_amdgcn_sinf(f);
        const bool up = (l & 2) != 0;
        const float sgn = up ? -1.0f : 1.0f;
        const float wc  = up ? c : 1.0f;
        const float ws  = up ? s : 0.0f;
#pragma unroll
        for (int k = 0; k < 8; ++k) {
            float pr = dppq<0x4E>(ar[k]);
            float pi = dppq<0x4E>(ai[k]);
            float qr = dppq<0x4E>(br[k]);
            float qi = dppq<0x4E>(bi[k]);
            float tr = fmaf(sgn, ar[k], pr);
            float ti = fmaf(sgn, ai[k], pi);
            float ur = fmaf(sgn, br[k], qr);
            float ui = fmaf(sgn, bi[k], qi);
            ar[k] = tr * wc + ti * ws;
            ai[k] = ti * wc - tr * ws;
            br[k] = ur * wc + ui * ws;
            bi[k] = ui * wc - ur * ws;
        }
    }
    {   // ---- stage 1: DPP quad_perm [1,0,3,2]; twiddle = 1 ----
        const bool up = (l & 1) != 0;
        const float sgn = up ? -1.0f : 1.0f;
#pragma unroll
        for (int k = 0; k < 8; ++k) {
            float pr = dppq<0xB1>(ar[k]);
            float pi = dppq<0xB1>(ai[k]);
            float qr = dppq<0xB1>(br[k]);
            float qi = dppq<0xB1>(bi[k]);
            ar[k] = fmaf(sgn, ar[k], pr);
            ai[k] = fmaf(sgn, ai[k], pi);
            br[k] = fmaf(sgn, br[k], qr);
            bi[k] = fmaf(sgn, bi[k], qi);
        }
    }
    // ---- per-lane twiddle + in-register DFT8 ----
    const int w = __brev((unsigned)l) >> 26;
#pragma unroll
    for (int k = 1; k < 8; ++k) {
        const float f = (float)(k * w) * (1.0f / 512.0f);
        const float c = __builtin_amdgcn_cosf(f);
        const float s = __builtin_amdgcn_sinf(f);
        float tr = ar[k] * c + ai[k] * s;
        float ti = ai[k] * c - ar[k] * s;
        ar[k] = tr; ai[k] = ti;
        float ur = br[k] * c + bi[k] * s;
        float ui = bi[k] * c - br[k] * s;
        br[k] = ur; bi[k] = ui;
    }
    dft8(ar, ai);
    dft8(br, bi);
}

// ---------------------------------------------------------------------------
// K1: grayscale + 2 packed row-pair FFTs per wave + Hermitian unpack +
// transposed write. NOW 256 thr = 4 waves = 16 rows/block, 34 KB LDS
// -> 4 blocks/CU (was 2) for deeper memory overlap. Epilogue = R4-verified
// 8-pair indexing.
// ---------------------------------------------------------------------------
__global__ __launch_bounds__(256) void k_gray_rowfft(
    const float* __restrict__ img, float2* __restrict__ buf) {
    __shared__ float sr[8][FSZ], si[8][FSZ];
    const int t = threadIdx.x, wv = t >> 6, l = t & 63;
    const int b = blockIdx.y, tile = blockIdx.x;   // rows tile*16..tile*16+15
    const size_t plane = (size_t)N * N;
    const float* base = img + (size_t)b * 3 * plane;
    const int r0 = tile * 16 + 4 * wv;             // this wave: rows r0..r0+3

    const float inv3 = 1.0f / 3.0f;
    auto loadgray = [&](const float* p, float (&g)[8]) {
        const float4* c0 = (const float4*)p;
        const float4* c1 = (const float4*)(p + plane);
        const float4* c2 = (const float4*)(p + 2 * plane);
#pragma unroll
        for (int q = 0; q < 2; ++q) {
            float4 a = c0[2 * l + q], bb = c1[2 * l + q], c = c2[2 * l + q];
            g[4 * q + 0] = (a.x + bb.x + c.x) * inv3;
            g[4 * q + 1] = (a.y + bb.y + c.y) * inv3;
            g[4 * q + 2] = (a.z + bb.z + c.z) * inv3;
            g[4 * q + 3] = (a.w + bb.w + c.w) * inv3;
        }
    };

    float arr[8], ari[8], brr[8], bri[8];
    loadgray(base + (size_t)(r0 + 0) * N, arr);    // FFT A: rows r0, r0+1
    loadgray(base + (size_t)(r0 + 1) * N, ari);
    loadgray(base + (size_t)(r0 + 2) * N, brr);    // FFT B: rows r0+2, r0+3
    loadgray(base + (size_t)(r0 + 3) * N, bri);

    fft512_x2(arr, ari, brr, bri, l);

    const int w = __brev((unsigned)l) >> 26;
    const int sA = 2 * wv, sB = 2 * wv + 1;        // pair slabs (2 rows each)
#pragma unroll
    for (int k = 0; k < 8; ++k) {
        int u = w + 64 * k;
        sr[sA][NPAD(u)] = arr[k]; si[sA][NPAD(u)] = ari[k];
        sr[sB][NPAD(u)] = brr[k]; si[sB][NPAD(u)] = bri[k];
    }
    __syncthreads();

    // unpack F_even/F_odd; lane emits both parities of pair p = t&7 as one
    // float4 (columns h2, h2+1 of the 16-row tile) for 9 v-slices (R4 shape).
    const int p = t & 7;
    const int h2 = 2 * p;
    const int slot = t >> 3;                       // 0..31
    float2* ob = buf + (size_t)b * NCOL * N;
#pragma unroll
    for (int it = 0; it < 9; ++it) {
        int v = slot + 32 * it;
        if (v < NCOL) {
            int vn = (N - v) & (N - 1);
            float Zr  = sr[p][NPAD(v)],  Zi  = si[p][NPAD(v)];
            float Zr2 = sr[p][NPAD(vn)], Zi2 = si[p][NPAD(vn)];
            float4 o;
            o.x = 0.5f * (Zr + Zr2);               // F_even.re
            o.y = 0.5f * (Zi - Zi2);               // F_even.im
            o.z = 0.5f * (Zi + Zi2);               // F_odd.re
            o.w = 0.5f * (Zr2 - Zr);               // F_odd.im
            *(float4*)(&ob[(size_t)v * N + tile * 16 + h2]) = o;
        }
    }
}

// ---------------------------------------------------------------------------
// K2: 2 column FFTs per wave + masked/total partial sums; XCD-aware 1D grid.
// (R13 verbatim)
// ---------------------------------------------------------------------------
__global__ __launch_bounds__(256) void k_colfft_reduce(
    const float2* __restrict__ buf, float2* __restrict__ part) {
    __shared__ float red[8];
    const int t = threadIdx.x, wv = t >> 6, l = t & 63;

    const unsigned id = blockIdx.x;            // 0..1055
    const int xcd  = (int)(id & 7u);
    const int slot = (int)(id >> 3);           // 0..131
    const int b = xcd + 8 * (slot / NG2);      // image 0..31
    const int g = slot % NG2;                  // column group 0..32

    const int v0 = g * 8 + 2 * wv;
    const int v1 = v0 + 1;
    const int c0 = v0 > 256 ? 256 : v0;
    const int c1 = v1 > 256 ? 256 : v1;

    const float4* colA = (const float4*)(buf + ((size_t)b * NCOL + c0) * N);
    const float4* colB = (const float4*)(buf + ((size_t)b * NCOL + c1) * N);
    float arr[8], ari[8], brr[8], bri[8];
#pragma unroll
    for (int q = 0; q < 4; ++q) {
        float4 zA = colA[4 * l + q];
        float4 zB = colB[4 * l + q];
        arr[2 * q] = zA.x; ari[2 * q] = zA.y;
        arr[2 * q + 1] = zA.z; ari[2 * q + 1] = zA.w;
        brr[2 * q] = zB.x; bri[2 * q] = zB.y;
        brr[2 * q + 1] = zB.z; bri[2 * q + 1] = zB.w;
    }

    fft512_x2(arr, ari, brr, bri, l);

    const float wA = (v0 == 0 || v0 == 256) ? 1.0f : (v0 < 256 ? 2.0f : 0.0f);
    const float wB = (v1 == 256) ? 1.0f : (v1 < 256 ? 2.0f : 0.0f);
    const float dxA = (float)(c0 - 256), dxA2 = dxA * dxA;
    const float dxB = (float)(c1 - 256), dxB2 = dxB * dxB;
    const int w = __brev((unsigned)l) >> 26;
    float msum = 0.0f, tsum = 0.0f;
#pragma unroll
    for (int k = 0; k < 8; ++k) {
        int u = w + 64 * k;
        float dy = (float)(u - 256);
        float dy2 = dy * dy;
        float magA = sqrtf(arr[k] * arr[k] + ari[k] * ari[k]) * wA;
        float magB = sqrtf(brr[k] * brr[k] + bri[k] * bri[k]) * wB;
        tsum += magA + magB;
        float m = 0.0f;
        if (dy2 + dxA2 <= RAD2) m += magA;
        if (dy2 + dxB2 <= RAD2) m += magB;
        msum += m;
    }
#pragma unroll
    for (int off = 32; off > 0; off >>= 1) {
        msum += __shfl_down(msum, off);
        tsum += __shfl_down(tsum, off);
    }
    if (l == 0) { red[wv * 2] = msum; red[wv * 2 + 1] = tsum; }
    __syncthreads();
    if (t == 0) {
        float m = red[0] + red[2] + red[4] + red[6];
        float s = red[1] + red[3] + red[5] + red[7];
        part[g * 32 + b] = make_float2(m, s);  // plain store
    }
}

// ---------------------------------------------------------------------------
// K3: 256 threads — 8 lanes per image scan the 33 partials, shfl-reduce
// within the 8-lane group, then thread 0 averages the 32 ratios.
// ---------------------------------------------------------------------------
__global__ __launch_bounds__(256) void k_final(const float2* __restrict__ part,
                                               float* __restrict__ out) {
    __shared__ float ratios[32];
    const int t = threadIdx.x;
    const int im = t >> 3, sl = t & 7;         // 32 images x 8 slices
    float m = 0.0f, s = 0.0f;
    for (int g = sl; g < NG2; g += 8) {
        float2 p = part[g * 32 + im];
        m += p.x; s += p.y;
    }
#pragma unroll
    for (int off = 4; off >= 1; off >>= 1) {
        m += __shfl_down(m, off, 8);
        s += __shfl_down(s, off, 8);
    }
    if (sl == 0) ratios[im] = m / s;
    __syncthreads();
    if (t == 0) {
        float r = 0.0f;
#pragma unroll
        for (int i = 0; i < 32; ++i) r += ratios[i];
        out[0] = r * (1.0f / 32.0f);
    }
}

extern "C" void kernel_launch(void* const* d_in, const int* in_sizes, int n_in,
                              void* d_out, int out_size, void* d_ws,
                              size_t ws_size, hipStream_t stream) {
    const float* img = (const float*)d_in[0];
    float* out = (float*)d_out;

    float2* buf = (float2*)d_ws;               // [32][257][512] ~ 33.7MB
    const size_t buf_bytes = (size_t)32 * NCOL * N * sizeof(float2);
    float2* part = (float2*)((char*)d_ws + buf_bytes);  // [33][32] pairs

    dim3 g1(N / 16, 32);                       // 32 row-tiles x 32 images
    k_gray_rowfft<<<g1, 256, 0, stream>>>(img, buf);

    k_colfft_reduce<<<dim3(8 * 132), 256, 0, stream>>>(buf, part);

    k_final<<<1, 256, 0, stream>>>(part, out);
}